// Round 2
// 88.861 us; speedup vs baseline: 1.1109x; 1.1109x over previous
//
#include <hip/hip_runtime.h>
#include <hip/hip_bf16.h>
#include <hip/hip_fp16.h>

#define B_ 8
#define N_ 512
#define F_ 128
#define H_ 4
#define U_ 32
#define LEAKY_ALPHA 0.2f
#define PS 520     // pbf row stride (bf16 elems); 1040 B row -> 16B-aligned
#define RCPLN2 1.4426950408889634f

typedef __attribute__((ext_vector_type(8))) short short8;
typedef __attribute__((ext_vector_type(4))) float f32x4;
typedef _Float16 h2 __attribute__((ext_vector_type(2)));
typedef unsigned int u32;
typedef unsigned short u16;

static __device__ __forceinline__ short f2bf_s(float x) {
    __hip_bfloat16 hv = __float2bfloat16(x);
    return *reinterpret_cast<short*>(&hv);
}
static __device__ __forceinline__ float bf2f_s(short v) {
    return __uint_as_float(((unsigned)(unsigned short)v) << 16);
}
static __device__ __forceinline__ u16 f2h_s(float x) {
    __half h = __float2half(x);
    return *reinterpret_cast<u16*>(&h);
}
static __device__ __forceinline__ h2 u2h2(u32 v) {
    return __builtin_bit_cast(h2, v);
}

// ---------------------------------------------------------------------------
// Kernel 1: projections (f16 data paths for the packed Phase A).
//   sf16  = f16(x@Wsrc)            [bh][n][u]   (u-adjacent -> uniform dword
//                                                loads give (u,u+1) pairs)
//   dT16  = f16(-(x@Wdst))^T       [bh*32+u][n] (coalesced per-lane d-rows)
//   hsrcT = bf16(x@Wsrc)^T         [bh*32+u][n] (MFMA B-frag layout)
//   Drow[j] = (sum_u a_u d_ju) * RCPLN2 ; a2h = f16(0.8*a*RCPLN2)
// score/ln2 ~ D_j + sum_u a2_u max(s_iu, -d_ju); exp via v_exp_f32 (exp2).
// ---------------------------------------------------------------------------
__global__ __launch_bounds__(256) void proj_kernel(
    const float* __restrict__ x, const float* __restrict__ Wsrc,
    const float* __restrict__ Wdst, const float* __restrict__ a,
    float* __restrict__ Drow, u16* __restrict__ a2h,
    u16* __restrict__ sf16, u16* __restrict__ dT16,
    short* __restrict__ hsrcT)
{
    __shared__ float4 xlds[8 * 32];
    const int t  = threadIdx.x;
    const int r0 = blockIdx.x * 8;

    const float4* xg = (const float4*)x + (size_t)r0 * 32;
    xlds[t] = xg[t];
    __syncthreads();

    const int u     = t & 31;
    const int h     = (t >> 5) & 3;
    const int which = t >> 7;
    const float* W  = (which ? Wdst : Wsrc) + h * (F_ * U_) + u;

    float acc[8];
#pragma unroll
    for (int r = 0; r < 8; ++r) acc[r] = 0.f;

#pragma unroll 2
    for (int fc = 0; fc < 32; ++fc) {
        const float w0 = W[(4 * fc + 0) * U_];
        const float w1 = W[(4 * fc + 1) * U_];
        const float w2 = W[(4 * fc + 2) * U_];
        const float w3 = W[(4 * fc + 3) * U_];
#pragma unroll
        for (int r = 0; r < 8; ++r) {
            const float4 xv = xlds[r * 32 + fc];
            float s = acc[r];
            s = fmaf(xv.x, w0, s);
            s = fmaf(xv.y, w1, s);
            s = fmaf(xv.z, w2, s);
            s = fmaf(xv.w, w3, s);
            acc[r] = s;
        }
    }

    const float av = a[h * U_ + u];
    if (which == 1 && blockIdx.x == 0)
        a2h[h * U_ + u] = f2h_s((1.f - LEAKY_ALPHA) * av * RCPLN2);

    const int b  = r0 >> 9;
    const int n0 = r0 & (N_ - 1);
    const int bh = b * H_ + h;

    if (which == 0) {
        short8 pk;
#pragma unroll
        for (int r = 0; r < 8; ++r) pk[r] = f2bf_s(acc[r]);
        *(short8*)&hsrcT[((size_t)(bh * U_) + u) * N_ + n0] = pk;
#pragma unroll
        for (int r = 0; r < 8; ++r)
            sf16[((size_t)(bh * N_ + n0 + r) << 5) + u] = f2h_s(acc[r]);
    } else {
        short8 dk;
#pragma unroll
        for (int r = 0; r < 8; ++r) dk[r] = (short)f2h_s(-acc[r]);
        *(short8*)&dT16[((size_t)(bh * U_) + u) * N_ + n0] = dk;
#pragma unroll
        for (int r = 0; r < 8; ++r) {
            float v = acc[r] * av;
            v += __shfl_xor(v, 1);
            v += __shfl_xor(v, 2);
            v += __shfl_xor(v, 4);
            v += __shfl_xor(v, 8);
            v += __shfl_xor(v, 16);
            if (u == 0) Drow[bh * N_ + n0 + r] = v * RCPLN2;
        }
    }
}

// ---------------------------------------------------------------------------
// Kernel 2: attention. Block = 512 thr = 8 waves; lane = j owns one d-row as
// 16 PINNED packed-f16 pairs (32 values). s-rows and a2 are block-uniform ->
// compiler scalarizes (R8: SGPR=112). Phase A per (i, lane):
// 16 v_pk_max_f16 + 16 v_dot2_f32_f16 (f32 accum) + v_exp_f32 + bf16 cvt
// -> ~36 VALU vs ~70 in the f32 version. All builtins, no raw VOP3P asm
// (R1's raw-asm version miscomputed scores). Phase C: MFMA p @ srcT.
// Grid = 32 bh x 32 tiles(16 i) = 1024 blocks.
// ---------------------------------------------------------------------------
__global__ __launch_bounds__(512, 4) void attn_kernel(
    const float* __restrict__ Drow, const u16* __restrict__ a2h,
    const u32* __restrict__ sf16, const u16* __restrict__ dT16,
    const short* __restrict__ hsrcT, float* __restrict__ out)
{
    __shared__ __align__(16) short pbf[16 * PS];  // 16.6 KB p bf16 [i][j]
    __shared__ f32x4 scr[8][64];                  // 8 KB K-partials
    __shared__ float lfin[16];                    // 1/l per i

    const int t    = threadIdx.x;
    const int L    = t & 63;
    const int w    = __builtin_amdgcn_readfirstlane(t >> 6);
    const int tile = blockIdx.x & 31;
    const int bh   = blockIdx.x >> 5;
    const int h    = bh & 3;
    const int b    = bh >> 2;
    const size_t bhN = (size_t)bh * N_;
    const int ig0  = tile * 16;
    const int j    = t;                           // lane owns column j

    // ---- per-lane d-row: 32 f16 loads (coalesced), packed to 16 pairs ----
    const u16* dT = dT16 + ((size_t)bh * U_) * N_ + j;
#define DL2(p) u32 dd##p = (u32)dT[(2*(p)) * N_] | ((u32)dT[(2*(p)+1) * N_] << 16);
    DL2(0) DL2(1) DL2(2)  DL2(3)  DL2(4)  DL2(5)  DL2(6)  DL2(7)
    DL2(8) DL2(9) DL2(10) DL2(11) DL2(12) DL2(13) DL2(14) DL2(15)
#undef DL2
    // Pin: sever the memory link so the compiler CANNOT re-materialize.
#define PIN4(a0,a1,a2,a3) asm volatile("" : "+v"(a0), "+v"(a1), "+v"(a2), "+v"(a3));
    PIN4(dd0,dd1,dd2,dd3)     PIN4(dd4,dd5,dd6,dd7)
    PIN4(dd8,dd9,dd10,dd11)   PIN4(dd12,dd13,dd14,dd15)
#undef PIN4

    const float Dj = Drow[bhN + j];                   // pre-scaled by 1/ln2
    const u32* sB = sf16 + ((bhN + (size_t)ig0) << 4);  // 16 rows x 16 pairs
    const h2* aH = (const h2*)a2h + h * (U_ / 2);     // block-uniform
    const h2 a0 = aH[0],  a1 = aH[1],  a2 = aH[2],  a3 = aH[3];
    const h2 a4 = aH[4],  a5 = aH[5],  a6 = aH[6],  a7 = aH[7];
    const h2 a8 = aH[8],  a9 = aH[9],  a10 = aH[10], a11 = aH[11];
    const h2 a12 = aH[12], a13 = aH[13], a14 = aH[14], a15 = aH[15];

    // 2 u-terms per (pk_max, dot2) pair; builtins -> compiler-correct codegen.
#define PK(k, ak, ddk, accv) {                                                \
    const h2 m_ = __builtin_elementwise_max(sR[k], u2h2(ddk));                \
    accv = __builtin_amdgcn_fdot2(ak, m_, accv, false); }
#pragma unroll 2
    for (int i = 0; i < 16; ++i) {
        const h2* sR = (const h2*)(sB + (i << 4));    // uniform -> s_load
        float acA = Dj, acB = 0.f;
        PK(0,  a0,  dd0,  acA) PK(1,  a1,  dd1,  acB)
        PK(2,  a2,  dd2,  acA) PK(3,  a3,  dd3,  acB)
        PK(4,  a4,  dd4,  acA) PK(5,  a5,  dd5,  acB)
        PK(6,  a6,  dd6,  acA) PK(7,  a7,  dd7,  acB)
        PK(8,  a8,  dd8,  acA) PK(9,  a9,  dd9,  acB)
        PK(10, a10, dd10, acA) PK(11, a11, dd11, acB)
        PK(12, a12, dd12, acA) PK(13, a13, dd13, acB)
        PK(14, a14, dd14, acA) PK(15, a15, dd15, acB)
        const float e = __builtin_amdgcn_exp2f(acA + acB);
        pbf[i * PS + j] = f2bf_s(e);
    }
#undef PK
    __syncthreads();

    // ---- l reduce: thread (ri = t>>5, rg = t&31) sums 16 j's of row ri ----
    {
        const int ri = t >> 5;
        const int rg = t & 31;
        const short8* pr = (const short8*)(pbf + ri * PS + rg * 16);
        const short8 pa = pr[0];
        const short8 pb = pr[1];
        float sum = 0.f;
#pragma unroll
        for (int k = 0; k < 8; ++k) sum += bf2f_s(pa[k]) + bf2f_s(pb[k]);
        sum += __shfl_xor(sum, 1);
        sum += __shfl_xor(sum, 2);
        sum += __shfl_xor(sum, 4);
        sum += __shfl_xor(sum, 8);
        sum += __shfl_xor(sum, 16);
        if (rg == 0) lfin[ri] = __builtin_amdgcn_rcpf(sum);
    }

    // ---- Phase C: MFMA  out = p @ src ; wave w = (nt = w&1, ks = w>>1) ----
    const int m  = L & 15;
    const int kq = L >> 4;
    const int nt = w & 1;
    const int ks = w >> 1;
    const short* Ap = pbf + m * PS + ks * 128 + kq * 8;
    const short* Bp = hsrcT + ((size_t)bh * U_ + nt * 16 + m) * N_ + ks * 128 + kq * 8;

    f32x4 acc = {0.f, 0.f, 0.f, 0.f};
#pragma unroll
    for (int st = 0; st < 4; ++st) {
        const short8 af = *(const short8*)(Ap + st * 32);
        const short8 bf = *(const short8*)(Bp + st * 32);
        acc = __builtin_amdgcn_mfma_f32_16x16x32_bf16(af, bf, acc, 0, 0, 0);
    }
    scr[w][L] = acc;
    __syncthreads();

    if (w < 2) {                               // wave w reduces ntile=w
        f32x4 s0 = scr[w][L];
        const f32x4 s1 = scr[w + 2][L];
        const f32x4 s2 = scr[w + 4][L];
        const f32x4 s3 = scr[w + 6][L];
        s0 += s1; s0 += s2; s0 += s3;
#pragma unroll
        for (int r = 0; r < 4; ++r) {
            const int il = kq * 4 + r;         // C/D: row=(lane>>4)*4+reg
            out[((size_t)(b * N_ + ig0 + il)) * (H_ * U_) + h * U_ + w * 16 + m]
                = s0[r] * lfin[il];
        }
    }
}

// ---------------------------------------------------------------------------
extern "C" void kernel_launch(void* const* d_in, const int* in_sizes, int n_in,
                              void* d_out, int out_size, void* d_ws, size_t ws_size,
                              hipStream_t stream) {
    const float* x    = (const float*)d_in[0];
    const float* Wsrc = (const float*)d_in[1];
    const float* Wdst = (const float*)d_in[2];
    const float* a    = (const float*)d_in[3];

    float* ws    = (float*)d_ws;
    float* Drow  = ws;                                  // 16384 f   (64 KB)
    u16*   a2h   = (u16*)(Drow + (size_t)B_ * H_ * N_); // 128 us
    u16*   sf16  = a2h + 128;                           // 524288 us (1 MB)
    u16*   dT16  = sf16 + (size_t)B_ * H_ * N_ * U_;    // 524288 us (1 MB)
    short* hsrcT = (short*)(dT16 + (size_t)B_ * H_ * U_ * N_); // 1 MB

    proj_kernel<<<(B_ * N_) / 8, 256, 0, stream>>>(x, Wsrc, Wdst, a,
                                                   Drow, a2h, sf16, dT16,
                                                   hsrcT);
    attn_kernel<<<B_ * H_ * (N_ / 16), 512, 0, stream>>>(Drow, a2h,
                                                         (const u32*)sf16,
                                                         dT16, hsrcT,
                                                         (float*)d_out);
}